// Round 1
// baseline (122.744 us; speedup 1.0000x reference)
//
#include <hip/hip_runtime.h>

#define NROWS  32768
#define ROWLEN 1024
#define L1LEN  519
#define L2LEN  267
#define L3LEN  141
#define NBLK   2048

// out[i] = sum_k in[sym(2i + k - 14)] * F[15-k]
// G[k] = LO[15-k] (approx filter, pre-reversed), H[k] = (-1)^k * LO[k] (detail, pre-reversed)
__device__ __forceinline__ float2 dwt_tap16(const float* __restrict__ in, int L, int i) {
    constexpr float G[16] = {
        0.05441584224308161f,     0.3128715909144659f,     0.6756307362980128f,    0.5853546836548691f,
       -0.015829105256023893f,   -0.2840155429624281f,     0.00047248457399797254f,0.128747426620186f,
       -0.01736930100202211f,    -0.04408825393106472f,    0.013981027917015516f,  0.008746094047015655f,
       -0.00487035299301066f,    -0.0003917403729959771f,  0.0006754494059985568f,-0.00011747678400228192f
    };
    constexpr float H[16] = {
       -0.00011747678400228192f, -0.0006754494059985568f, -0.0003917403729959771f, 0.00487035299301066f,
        0.008746094047015655f,   -0.013981027917015516f,  -0.04408825393106472f,   0.01736930100202211f,
        0.128747426620186f,      -0.00047248457399797254f,-0.2840155429624281f,    0.015829105256023893f,
        0.5853546836548691f,     -0.6756307362980128f,     0.3128715909144659f,   -0.05441584224308161f
    };
    const int base = 2 * i - 14;
    float a = 0.f, d = 0.f;
    if (base >= 0 && base + 15 < L) {
#pragma unroll
        for (int k = 0; k < 16; ++k) {
            float v = in[base + k];
            a = fmaf(v, G[k], a);
            d = fmaf(v, H[k], d);
        }
    } else {
#pragma unroll
        for (int k = 0; k < 16; ++k) {
            int idx = base + k;
            idx = (idx < 0) ? (-idx - 1) : ((idx >= L) ? (2 * L - 1 - idx) : idx);
            float v = in[idx];
            a = fmaf(v, G[k], a);
            d = fmaf(v, H[k], d);
        }
    }
    return make_float2(a, d);
}

__global__ __launch_bounds__(256) void combined_loss_kernel(
    const float* __restrict__ x, const float* __restrict__ y,
    float* __restrict__ partials)
{
    __shared__ float xs[ROWLEN];
    __shared__ float es[ROWLEN];
    __shared__ float a1[L1LEN + 1];
    __shared__ float a2[L2LEN + 1];
    __shared__ float wsum[4];

    const int tid = threadIdx.x;
    float s_mse = 0.f, s_spec = 0.f, s_d1 = 0.f, s_d2 = 0.f, s_d3 = 0.f;

    for (int row = blockIdx.x; row < NROWS; row += NBLK) {
        const float4 xv = ((const float4*)(x + (size_t)row * ROWLEN))[tid];
        const float4 yv = ((const float4*)(y + (size_t)row * ROWLEN))[tid];
        const float4 ev = make_float4(xv.x - yv.x, xv.y - yv.y, xv.z - yv.z, xv.w - yv.w);
        ((float4*)xs)[tid] = xv;
        ((float4*)es)[tid] = ev;
        s_mse += ev.x * ev.x + ev.y * ev.y + ev.z * ev.z + ev.w * ev.w;
        __syncthreads();  // S1: xs/es visible

        // spectral: sd_i = x[i] - 2x[i+1] + x[i+2], i in [0, 1021]; this thread owns i = 4*tid..4*tid+3
        {
            float sd0 = xv.x - 2.f * xv.y + xv.z;
            float sd1 = xv.y - 2.f * xv.z + xv.w;
            s_spec += sd0 * sd0 + sd1 * sd1;
            if (tid < 255) {
                float n0 = xs[4 * tid + 4];
                float n1 = xs[4 * tid + 5];
                float sd2 = xv.z - 2.f * xv.w + n0;
                float sd3 = xv.w - 2.f * n0 + n1;
                s_spec += sd2 * sd2 + sd3 * sd3;
            }
        }

        // level 1: es(1024) -> a1(519), accumulate cD^2
        for (int i = tid; i < L1LEN; i += 256) {
            float2 ad = dwt_tap16(es, ROWLEN, i);
            a1[i] = ad.x;
            s_d1 += ad.y * ad.y;
        }
        __syncthreads();  // S2: a1 ready, es readers done

        // level 2: a1(519) -> a2(267)
        for (int i = tid; i < L2LEN; i += 256) {
            float2 ad = dwt_tap16(a1, L1LEN, i);
            a2[i] = ad.x;
            s_d2 += ad.y * ad.y;
        }
        __syncthreads();  // S3: a2 ready

        // level 3: a2(267), cD only
        for (int i = tid; i < L3LEN; i += 256) {
            float2 ad = dwt_tap16(a2, L2LEN, i);
            s_d3 += ad.y * ad.y;
        }
        // no sync needed: next S1 orders everything (each thread writes only its own xs/es slots)
    }

    // fold with exact reference denominators
    const float wm  = 1.0f / 33554432.0f;             // 32*1024*1024
    const float wsp = 1.0f / 33488896.0f;             // 32*1024*1022
    const float w1  = 1.0f / (3.0f * 17006592.0f);    // 32768*519
    const float w2  = 1.0f / (3.0f * 8749056.0f);     // 32768*267
    const float w3  = 1.0f / (3.0f * 4620288.0f);     // 32768*141
    float local = wm * s_mse + wsp * s_spec + w1 * s_d1 + w2 * s_d2 + w3 * s_d3;

#pragma unroll
    for (int off = 32; off > 0; off >>= 1)
        local += __shfl_down(local, off, 64);
    __syncthreads();  // protect wsum vs any stragglers (paranoia; wsum unused above)
    if ((tid & 63) == 0) wsum[tid >> 6] = local;
    __syncthreads();
    if (tid == 0) partials[blockIdx.x] = wsum[0] + wsum[1] + wsum[2] + wsum[3];
}

__global__ __launch_bounds__(256) void reduce_kernel(const float* __restrict__ partials,
                                                     int n, float* __restrict__ out)
{
    __shared__ double sm[256];
    double s = 0.0;
    for (int i = threadIdx.x; i < n; i += 256) s += (double)partials[i];
    sm[threadIdx.x] = s;
    __syncthreads();
    for (int off = 128; off > 0; off >>= 1) {
        if (threadIdx.x < off) sm[threadIdx.x] += sm[threadIdx.x + off];
        __syncthreads();
    }
    if (threadIdx.x == 0) out[0] = (float)sm[0];
}

extern "C" void kernel_launch(void* const* d_in, const int* in_sizes, int n_in,
                              void* d_out, int out_size, void* d_ws, size_t ws_size,
                              hipStream_t stream) {
    const float* x = (const float*)d_in[0];   // output
    const float* y = (const float*)d_in[1];   // target
    float* partials = (float*)d_ws;           // NBLK floats
    combined_loss_kernel<<<NBLK, 256, 0, stream>>>(x, y, partials);
    reduce_kernel<<<1, 256, 0, stream>>>(partials, NBLK, (float*)d_out);
}